// Round 4
// baseline (2205.263 us; speedup 1.0000x reference)
//
#include <hip/hip_runtime.h>
#include <hip/hip_bf16.h>
#include <stdint.h>

// Problem constants (SparseMoE: B=4, T=4096, C=1024, E=8, H=4C, topk=2)
#define NC 1024
#define NE 8
#define NH 4096
#define NN 16384   // B*T tokens

typedef __bf16 bf16x8_t __attribute__((ext_vector_type(8)));
typedef float f32x4_t __attribute__((ext_vector_type(4)));

// Convert 8 fp32 -> 8 bf16, write 16B to LDS/global.
__device__ __forceinline__ void cvt8(const float4 a, const float4 b, __bf16* dst) {
  bf16x8_t r;
  r[0] = (__bf16)a.x; r[1] = (__bf16)a.y; r[2] = (__bf16)a.z; r[3] = (__bf16)a.w;
  r[4] = (__bf16)b.x; r[5] = (__bf16)b.y; r[6] = (__bf16)b.z; r[7] = (__bf16)b.w;
  *(bf16x8_t*)dst = r;
}

// ---------------- routing (fp32 exact, double accum): noisy top-2, probs, expert lists ----------------
__global__ __launch_bounds__(256) void routing_kernel(
    const float* __restrict__ x, const float* __restrict__ eps,
    const float* __restrict__ rw, const float* __restrict__ rb,
    const float* __restrict__ nw, const float* __restrict__ nb,
    int* __restrict__ counts, int* __restrict__ perm, float* __restrict__ pprob) {
  const int lane = threadIdx.x & 63;
  const int n = blockIdx.x * 4 + (threadIdx.x >> 6);  // one wave per token
  if (n >= NN) return;
  double acc[16];
#pragma unroll
  for (int i = 0; i < 16; ++i) acc[i] = 0.0;
  const float* xr = x + (size_t)n * NC;
  for (int c0 = 0; c0 < NC; c0 += 64) {
    const int c = c0 + lane;
    const float xv = xr[c];
    const float4 r0 = *(const float4*)(rw + (size_t)c * NE);
    const float4 r1 = *(const float4*)(rw + (size_t)c * NE + 4);
    const float4 n0 = *(const float4*)(nw + (size_t)c * NE);
    const float4 n1 = *(const float4*)(nw + (size_t)c * NE + 4);
    acc[0] += (double)xv * r0.x;  acc[1] += (double)xv * r0.y;
    acc[2] += (double)xv * r0.z;  acc[3] += (double)xv * r0.w;
    acc[4] += (double)xv * r1.x;  acc[5] += (double)xv * r1.y;
    acc[6] += (double)xv * r1.z;  acc[7] += (double)xv * r1.w;
    acc[8] += (double)xv * n0.x;  acc[9] += (double)xv * n0.y;
    acc[10] += (double)xv * n0.z; acc[11] += (double)xv * n0.w;
    acc[12] += (double)xv * n1.x; acc[13] += (double)xv * n1.y;
    acc[14] += (double)xv * n1.z; acc[15] += (double)xv * n1.w;
  }
#pragma unroll
  for (int off = 32; off > 0; off >>= 1) {
#pragma unroll
    for (int i = 0; i < 16; ++i) acc[i] += __shfl_xor(acc[i], off, 64);
  }
  if (lane == 0) {
    double noisy[NE];
#pragma unroll
    for (int e = 0; e < NE; ++e) {
      const double lg = acc[e] + (double)rb[e];
      const double z = acc[8 + e] + (double)nb[e];
      const double sp = log1p(exp(-fabs(z))) + fmax(z, 0.0);  // stable softplus
      noisy[e] = lg + (double)eps[(size_t)n * NE + e] * sp;
    }
    int i1 = -1, i2 = -1;
    double v1 = -1e300, v2 = -1e300;
#pragma unroll
    for (int e = 0; e < NE; ++e) {  // strict > keeps earlier index on ties (lax.top_k)
      const double v = noisy[e];
      if (v > v1) { v2 = v1; i2 = i1; v1 = v; i1 = e; }
      else if (v > v2) { v2 = v; i2 = e; }
    }
    if (i1 < 0) i1 = 0;                       // hardening vs pathological inputs
    if (i2 < 0 || i2 == i1) i2 = (i1 + 1) & 7;
    const double d = exp(v2 - v1);
    const float p1 = (float)(1.0 / (1.0 + d));
    const float p2 = (float)(d / (1.0 + d));
    int pos = atomicAdd(&counts[i1], 1);
    if (pos >= 0 && pos < NN) { perm[i1 * NN + pos] = n; pprob[i1 * NN + pos] = p1; }
    pos = atomicAdd(&counts[i2], 1);
    if (pos >= 0 && pos < NN) { perm[i2 * NN + pos] = n; pprob[i2 * NN + pos] = p2; }
  }
}

// ---------------- transpose + fp32->bf16: src fp32 [R][Cc] -> dst bf16 [Cc][R] ----------------
__global__ __launch_bounds__(256) void transpose_cvt(
    const float* __restrict__ src, __bf16* __restrict__ dst, int R, int Cc) {
  __shared__ __align__(16) __bf16 tile[64][72];  // +8 pad
  const int r0 = blockIdx.y * 64, c0 = blockIdx.x * 64;
  const int t = threadIdx.x;
  const int tr = t >> 3;            // 0..31
  const int tc = (t & 7) * 8;       // 0..56
#pragma unroll
  for (int h = 0; h < 2; ++h) {
    const int r = tr + h * 32;
    const float* sp = src + (size_t)(r0 + r) * Cc + (c0 + tc);
    const float4 a = *(const float4*)sp;
    const float4 b = *(const float4*)(sp + 4);
    cvt8(a, b, &tile[r][tc]);
  }
  __syncthreads();
#pragma unroll
  for (int h = 0; h < 2; ++h) {
    const int c = tr + h * 32;
    __bf16 tmp[8] __attribute__((aligned(16)));
#pragma unroll
    for (int j = 0; j < 8; ++j) tmp[j] = tile[tc + j][c];
    __bf16* dp = dst + (size_t)(c0 + c) * R + (r0 + tc);
    *(uint4*)dp = *(const uint4*)tmp;
  }
}

// ---------------- GEMM1: h = relu(gather(x) @ w1e + b1), bf16 MFMA ----------------
// FASTB: bsrc = bf16 [NH][NC] pre-transposed (k-contiguous rows).
// !FASTB: bsrc = fp32 [NC][NH] as given (n-contiguous rows), inline cvt.
template<bool FASTB>
__global__ __launch_bounds__(256) void moe_gemm1(
    const float* __restrict__ x, const void* __restrict__ bsrc,
    const float* __restrict__ bias, __bf16* __restrict__ hbuf,
    const int* __restrict__ counts_e, const int* __restrict__ perm_e, int chunk_start) {
  int cnt = *counts_e; if (cnt > NN) cnt = NN; if (cnt < 0) cnt = 0;
  const int lr0 = blockIdx.y * 128;
  const int row0 = chunk_start + lr0;
  if (row0 >= cnt) return;
  const int t = threadIdx.x;

  __shared__ __align__(16) __bf16 As[128 * 32];  // [m][k]
  __shared__ __align__(16) __bf16 Bs[128 * 32];  // FASTB: [n][k]; else [k][n]

  const int ar1 = row0 + (t >> 2), ar2 = ar1 + 64;
  const int tokA = (ar1 < cnt) ? perm_e[ar1] : 0;
  const int tokB = (ar2 < cnt) ? perm_e[ar2] : 0;
  const int kg = (t & 3) * 8;
  const float* pA1 = x + (size_t)tokA * NC + kg;
  const float* pA2 = x + (size_t)tokB * NC + kg;
  const int n0 = blockIdx.x * 128;

  const __bf16* pB1 = nullptr; const __bf16* pB2 = nullptr;  // FASTB
  const float* pBw = nullptr;                                 // !FASTB
  const int kk = t >> 3, cc = (t & 7) * 16;
  if (FASTB) {
    const __bf16* bt = (const __bf16*)bsrc;
    const int nrow = n0 + (t >> 2);
    pB1 = bt + (size_t)nrow * NC + kg;
    pB2 = bt + (size_t)(nrow + 64) * NC + kg;
  } else {
    pBw = (const float*)bsrc + (size_t)kk * NH + n0 + cc;
  }

  f32x4_t acc[4][4];
#pragma unroll
  for (int i = 0; i < 4; ++i)
#pragma unroll
    for (int j = 0; j < 4; ++j)
#pragma unroll
      for (int k = 0; k < 4; ++k) acc[i][j][k] = 0.f;

  const int lane = t & 63, wid = t >> 6;
  const int wm = (wid >> 1) * 64, wn = (wid & 1) * 64;
  const int col16 = lane & 15, quad = lane >> 4;
  const int a_off = (wm + col16) * 32 + quad * 8;
  const int b_off = (wn + col16) * 32 + quad * 8;

  for (int k0 = 0; k0 < NC; k0 += 32) {
    const float4 a1a = *(const float4*)(pA1 + k0);
    const float4 a1b = *(const float4*)(pA1 + k0 + 4);
    const float4 a2a = *(const float4*)(pA2 + k0);
    const float4 a2b = *(const float4*)(pA2 + k0 + 4);
    uint4 vb1, vb2; float4 w0, w1, w2, w3;
    if (FASTB) {
      vb1 = *(const uint4*)(pB1 + k0);
      vb2 = *(const uint4*)(pB2 + k0);
    } else {
      const float* pw = pBw + (size_t)k0 * NH;
      w0 = *(const float4*)pw; w1 = *(const float4*)(pw + 4);
      w2 = *(const float4*)(pw + 8); w3 = *(const float4*)(pw + 12);
    }
    __syncthreads();
    cvt8(a1a, a1b, As + t * 8);
    cvt8(a2a, a2b, As + 2048 + t * 8);
    if (FASTB) {
      *(uint4*)(Bs + t * 8) = vb1;
      *(uint4*)(Bs + 2048 + t * 8) = vb2;
    } else {
      cvt8(w0, w1, Bs + kk * 128 + cc);
      cvt8(w2, w3, Bs + kk * 128 + cc + 8);
    }
    __syncthreads();
    bf16x8_t af[4], bfr[4];
#pragma unroll
    for (int mi = 0; mi < 4; ++mi) af[mi] = *(const bf16x8_t*)(As + a_off + mi * 512);
    if (FASTB) {
#pragma unroll
      for (int ni = 0; ni < 4; ++ni) bfr[ni] = *(const bf16x8_t*)(Bs + b_off + ni * 512);
    } else {
#pragma unroll
      for (int ni = 0; ni < 4; ++ni) {
        const int bn = wn + ni * 16 + col16;
#pragma unroll
        for (int j = 0; j < 8; ++j) bfr[ni][j] = Bs[(quad * 8 + j) * 128 + bn];
      }
    }
#pragma unroll
    for (int mi = 0; mi < 4; ++mi)
#pragma unroll
      for (int ni = 0; ni < 4; ++ni)
        acc[mi][ni] = __builtin_amdgcn_mfma_f32_16x16x32_bf16(af[mi], bfr[ni], acc[mi][ni], 0, 0, 0);
  }

  // C/D: col = lane&15, row = quad*4 + reg (m89-verified)
  const int colbase = n0 + wn + col16;
#pragma unroll
  for (int mi = 0; mi < 4; ++mi)
#pragma unroll
    for (int reg = 0; reg < 4; ++reg) {
      const int lr = lr0 + wm + mi * 16 + quad * 4 + reg;
      if (chunk_start + lr < cnt) {
        __bf16* hp = hbuf + (size_t)lr * NH + colbase;
#pragma unroll
        for (int ni = 0; ni < 4; ++ni) {
          const float v = acc[mi][ni][reg] + bias[colbase + ni * 16];
          hp[ni * 16] = (__bf16)fmaxf(v, 0.f);
        }
      }
    }
}

// ---------------- GEMM2: out[tok] += p * (h @ w2e + b2), fp32 out ----------------
// FASTB: bsrc = bf16 [NC][NH] pre-transposed. !FASTB: bsrc = fp32 [NH][NC].
template<bool FASTB>
__global__ __launch_bounds__(256) void moe_gemm2(
    const __bf16* __restrict__ hbuf, const void* __restrict__ bsrc,
    const float* __restrict__ bias, float* __restrict__ out,
    const int* __restrict__ counts_e, const int* __restrict__ perm_e,
    const float* __restrict__ pprob_e, int chunk_start) {
  int cnt = *counts_e; if (cnt > NN) cnt = NN; if (cnt < 0) cnt = 0;
  const int lr0 = blockIdx.y * 128;
  if (chunk_start + lr0 >= cnt) return;
  const int t = threadIdx.x;

  __shared__ __align__(16) __bf16 As[128 * 32];
  __shared__ __align__(16) __bf16 Bs[128 * 32];

  const int lar1 = lr0 + (t >> 2);
  const int kg = (t & 3) * 8;
  const __bf16* pA1 = hbuf + (size_t)lar1 * NH + kg;
  const __bf16* pA2 = pA1 + (size_t)64 * NH;
  const int n0 = blockIdx.x * 128;

  const __bf16* pB1 = nullptr; const __bf16* pB2 = nullptr;
  const float* pBw = nullptr;
  const int kk = t >> 3, cc = (t & 7) * 16;
  if (FASTB) {
    const __bf16* bt = (const __bf16*)bsrc;
    const int nrow = n0 + (t >> 2);
    pB1 = bt + (size_t)nrow * NH + kg;
    pB2 = bt + (size_t)(nrow + 64) * NH + kg;
  } else {
    pBw = (const float*)bsrc + (size_t)kk * NC + n0 + cc;
  }

  f32x4_t acc[4][4];
#pragma unroll
  for (int i = 0; i < 4; ++i)
#pragma unroll
    for (int j = 0; j < 4; ++j)
#pragma unroll
      for (int k = 0; k < 4; ++k) acc[i][j][k] = 0.f;

  const int lane = t & 63, wid = t >> 6;
  const int wm = (wid >> 1) * 64, wn = (wid & 1) * 64;
  const int col16 = lane & 15, quad = lane >> 4;
  const int a_off = (wm + col16) * 32 + quad * 8;
  const int b_off = (wn + col16) * 32 + quad * 8;

  for (int k0 = 0; k0 < NH; k0 += 32) {
    const uint4 va1 = *(const uint4*)(pA1 + k0);
    const uint4 va2 = *(const uint4*)(pA2 + k0);
    uint4 vb1, vb2; float4 w0, w1, w2, w3;
    if (FASTB) {
      vb1 = *(const uint4*)(pB1 + k0);
      vb2 = *(const uint4*)(pB2 + k0);
    } else {
      const float* pw = pBw + (size_t)k0 * NC;
      w0 = *(const float4*)pw; w1 = *(const float4*)(pw + 4);
      w2 = *(const float4*)(pw + 8); w3 = *(const float4*)(pw + 12);
    }
    __syncthreads();
    *(uint4*)(As + t * 8) = va1;
    *(uint4*)(As + 2048 + t * 8) = va2;
    if (FASTB) {
      *(uint4*)(Bs + t * 8) = vb1;
      *(uint4*)(Bs + 2048 + t * 8) = vb2;
    } else {
      cvt8(w0, w1, Bs + kk * 128 + cc);
      cvt8(w2, w3, Bs + kk * 128 + cc + 8);
    }
    __syncthreads();
    bf16x8_t af[4], bfr[4];
#pragma unroll
    for (int mi = 0; mi < 4; ++mi) af[mi] = *(const bf16x8_t*)(As + a_off + mi * 512);
    if (FASTB) {
#pragma unroll
      for (int ni = 0; ni < 4; ++ni) bfr[ni] = *(const bf16x8_t*)(Bs + b_off + ni * 512);
    } else {
#pragma unroll
      for (int ni = 0; ni < 4; ++ni) {
        const int bn = wn + ni * 16 + col16;
#pragma unroll
        for (int j = 0; j < 8; ++j) bfr[ni][j] = Bs[(quad * 8 + j) * 128 + bn];
      }
    }
#pragma unroll
    for (int mi = 0; mi < 4; ++mi)
#pragma unroll
      for (int ni = 0; ni < 4; ++ni)
        acc[mi][ni] = __builtin_amdgcn_mfma_f32_16x16x32_bf16(af[mi], bfr[ni], acc[mi][ni], 0, 0, 0);
  }

  const int colbase = n0 + wn + col16;
#pragma unroll
  for (int mi = 0; mi < 4; ++mi)
#pragma unroll
    for (int reg = 0; reg < 4; ++reg) {
      const int lr = lr0 + wm + mi * 16 + quad * 4 + reg;
      const int r = chunk_start + lr;
      if (r < cnt) {
        const int tok = perm_e[r];
        const float p = pprob_e[r];
        float* op = out + (size_t)tok * NC + colbase;
#pragma unroll
        for (int ni = 0; ni < 4; ++ni) {
          op[ni * 16] += (acc[mi][ni][reg] + bias[colbase + ni * 16]) * p;  // one writer per (tok,col) per launch
        }
      }
    }
}

extern "C" void kernel_launch(void* const* d_in, const int* in_sizes, int n_in,
                              void* d_out, int out_size, void* d_ws, size_t ws_size,
                              hipStream_t stream) {
  (void)in_sizes; (void)n_in;
  const float* x   = (const float*)d_in[0];
  const float* eps = (const float*)d_in[1];
  const float* rw  = (const float*)d_in[2];
  const float* rb  = (const float*)d_in[3];
  const float* nw  = (const float*)d_in[4];
  const float* nb  = (const float*)d_in[5];
  const float* w1  = (const float*)d_in[6];
  const float* b1  = (const float*)d_in[7];
  const float* w2  = (const float*)d_in[8];
  const float* b2  = (const float*)d_in[9];
  float* out = (float*)d_out;

  // ws: counts(256B) | perm [E][N] | pprob [E][N] | {w1t, w2t bf16 if fast} | hbuf bf16
  char* wsb = (char*)d_ws;
  int* counts = (int*)wsb;
  int* perm = (int*)(wsb + 256);
  float* pprob = (float*)(wsb + 256 + (size_t)NE * NN * 4);
  size_t off = 256 + (size_t)NE * NN * 8;  // ~1.05 MB

  const size_t wtile = (size_t)NC * NH * 2;  // 8 MB per transposed weight
  const bool fast = ws_size >= off + 2 * wtile + (size_t)128 * NH * 2 + (1u << 20);
  __bf16* w1t = nullptr; __bf16* w2t = nullptr;
  if (fast) {
    w1t = (__bf16*)(wsb + off); off += wtile;
    w2t = (__bf16*)(wsb + off); off += wtile;
  }
  __bf16* hbuf = (__bf16*)(wsb + off);
  const size_t remain = (ws_size > off) ? (ws_size - off) : 0;
  long rows_cap = (long)(remain / ((size_t)NH * 2));
  rows_cap = (rows_cap / 128) * 128;
  if (rows_cap > NN) rows_cap = NN;
  if (rows_cap < 128) rows_cap = 128;  // floor; needs ws >= ~2.1 MB

  hipMemsetAsync(counts, 0, 256, stream);
  hipMemsetAsync(d_out, 0, (size_t)out_size * 4, stream);

  routing_kernel<<<NN / 4, 256, 0, stream>>>(x, eps, rw, rb, nw, nb, counts, perm, pprob);

  const int nchunks = (int)((NN + rows_cap - 1) / rows_cap);
  for (int e = 0; e < NE; ++e) {
    const float* w1e = w1 + (size_t)e * NC * NH;  // [C][H] fp32
    const float* w2e = w2 + (size_t)e * NH * NC;  // [H][C] fp32
    if (fast) {
      transpose_cvt<<<dim3(NH / 64, NC / 64), 256, 0, stream>>>(w1e, w1t, NC, NH);
      transpose_cvt<<<dim3(NC / 64, NH / 64), 256, 0, stream>>>(w2e, w2t, NH, NC);
    }
    for (int ch = 0; ch < nchunks; ++ch) {
      const int cs = ch * (int)rows_cap;
      if (fast) {
        moe_gemm1<true><<<dim3(NH / 128, (unsigned)(rows_cap / 128)), 256, 0, stream>>>(
            x, w1t, b1 + (size_t)e * NH, hbuf, counts + e, perm + (size_t)e * NN, cs);
        moe_gemm2<true><<<dim3(NC / 128, (unsigned)(rows_cap / 128)), 256, 0, stream>>>(
            hbuf, w2t, b2 + (size_t)e * NC, out, counts + e, perm + (size_t)e * NN,
            pprob + (size_t)e * NN, cs);
      } else {
        moe_gemm1<false><<<dim3(NH / 128, (unsigned)(rows_cap / 128)), 256, 0, stream>>>(
            x, w1e, b1 + (size_t)e * NH, hbuf, counts + e, perm + (size_t)e * NN, cs);
        moe_gemm2<false><<<dim3(NC / 128, (unsigned)(rows_cap / 128)), 256, 0, stream>>>(
            hbuf, w2e, b2 + (size_t)e * NC, out, counts + e, perm + (size_t)e * NN,
            pprob + (size_t)e * NN, cs);
      }
    }
  }
}